// Round 5
// baseline (134.284 us; speedup 1.0000x reference)
//
#include <hip/hip_runtime.h>
#include <hip/hip_bf16.h>

// VariableSelectionNetwork fused kernel, round 5.
//
// Live computation (sel fc1/fc2 and the nvh,vho einsum are dead in the ref):
//   weights = softmax(LN(GLU(x @ sel_gate_w + b) + x))            [N,32]
//   y[n,v,o] = sigmoid(x*gw+gb)*(x*gw'+gb') + (x*sw+sb)           [N,32,256]
//   out[n,o] = sum_v weights[n,v] * LN_o(y)[.,v,.]                [N,256]
//
// R4 (LDS-staged weights) beat the 40µs fill kernels. Pipe model says Phase B
// is LDS-pipe-bound (~19µs): 8 ds_read_b128 + 12 ds_swizzle shuffles per
// v-iter per wave. R5 attacks the LDS pipe:
//   1. RPW=2: one weight read serves two rows (ds_read traffic halves).
//   2. DPP reductions (row_shr 1/2/4/8 + row_bcast15/31 + readlane63):
//      LN sums move from the DS pipe to the VALU pipe.
//   3. 2 blocks/CU (TPB=256, grid=512): barrier stalls decouple.

#define VDIM 32
#define ODIM 256
#define RPB  8           // rows per block
#define TPB  256         // 4 waves; wave w owns rows 2w, 2w+1
#define NCHUNK 16        // VDIM / CHUNK_V, CHUNK_V = 2

__device__ __forceinline__ float fast_sigmoid(float g) {
    return __builtin_amdgcn_rcpf(1.0f + __expf(-g));
}

// DPP-add: x += dpp_shifted(x), 0-filled for invalid source lanes.
template <int CTRL>
__device__ __forceinline__ float dpp_add(float x) {
    int s = __builtin_amdgcn_update_dpp(0, __builtin_bit_cast(int, x),
                                        CTRL, 0xF, 0xF, true);
    return x + __builtin_bit_cast(float, s);
}

// Wave64 sum -> uniform (SGPR) value via readlane 63. Pure VALU, no DS ops.
__device__ __forceinline__ float wave_sum(float x) {
    x = dpp_add<0x111>(x);   // row_shr:1
    x = dpp_add<0x112>(x);   // row_shr:2
    x = dpp_add<0x114>(x);   // row_shr:4
    x = dpp_add<0x118>(x);   // row_shr:8  -> lane 15/31/47/63 hold row sums
    x = dpp_add<0x142>(x);   // row_bcast:15 -> lane 31/63 hold half sums
    x = dpp_add<0x143>(x);   // row_bcast:31 -> lane 63 holds total
    return __builtin_bit_cast(float,
        __builtin_amdgcn_readlane(__builtin_bit_cast(int, x), 63));
}

__global__ void __launch_bounds__(TPB, 2) vsn_fused(
    const float* __restrict__ x,     // [N,32]
    const float* __restrict__ sgw,   // [32,64]
    const float* __restrict__ sgb,   // [64]
    const float* __restrict__ slg,   // [32]
    const float* __restrict__ slb,   // [32]
    const float* __restrict__ vgw,   // [32,512]
    const float* __restrict__ vgb,   // [32,512]
    const float* __restrict__ vsw,   // [32,256]
    const float* __restrict__ vsb,   // [32,256]
    const float* __restrict__ vlg,   // [32,256]
    const float* __restrict__ vlb,   // [32,256]
    float* __restrict__ out)         // [N,256]
{
    // Per 16KB chunk buffer (4096 floats), variables v=2c,2c+1:
    //   [0,1024) vgw | [1024,2048) vgb | [2048,2560) vsw | [2560,3072) vsb
    //   [3072,3584) vlg | [3584,4096) vlb
    __shared__ float wbuf[2][4096];          // 32KB double buffer
    __shared__ float x_s[RPB][VDIM];         // 1KB
    __shared__ float g_s[RPB][2 * VDIM];     // 2KB
    __shared__ float w_s[RPB][VDIM];         // 1KB

    const int tid  = threadIdx.x;
    const int row0 = blockIdx.x * RPB;

    // ---- staging sources: thread t covers float4 slots t, t+256, t+512, t+768 ----
    const float* sb[4];
    int ss[4];
    sb[0] = vgw + (tid << 2);                       ss[0] = 1024;  // vid [0,256)
    sb[1] = vgb + (tid << 2);                       ss[1] = 1024;  // vid [256,512)
    sb[2] = ((tid < 128) ? vsw : (vsb - 512)) + ((tid + 512 - 512) << 2); ss[2] = 512;
    sb[3] = ((tid < 128) ? vlg : (vlb - 512)) + ((tid + 768 - 768) << 2); ss[3] = 512;
    // note: for tid>=128, (vsb - 512) + tid*4 == vsb + (tid-128)*4; same for vlb.

    // ---- issue chunk-0 staging loads early (hide under Phase A) ----
    float4 st0[4];
    #pragma unroll
    for (int k = 0; k < 4; ++k) st0[k] = *(const float4*)sb[k];

    // ---- load x rows (8*32 = 256 floats) ----
    ((float*)x_s)[tid] = x[row0 * VDIM + tid];
    __syncthreads();

    // ---- Phase A1: g = x @ sel_gate_w + b (8 rows x 64 cols, 2 tasks/thread) ----
    #pragma unroll
    for (int it = 0; it < 2; ++it) {
        const int i = tid + it * TPB;
        const int r = i >> 6, j = i & 63;
        float acc = sgb[j];
        #pragma unroll
        for (int v = 0; v < VDIM; ++v)
            acc = fmaf(x_s[r][v], sgw[v * 64 + j], acc);
        g_s[r][j] = acc;
    }
    __syncthreads();

    // ---- write chunk 0 into buffer 0; Phase A2 on all threads ----
    #pragma unroll
    for (int k = 0; k < 4; ++k)
        ((float4*)wbuf[0])[tid + k * TPB] = st0[k];

    {
        const int r = tid >> 5, v = tid & 31;    // 256 tasks == TPB
        const float gate = g_s[r][v];
        const float val  = g_s[r][VDIM + v];
        const float y    = fast_sigmoid(gate) * val + x_s[r][v];
        float s1 = y, s2 = y * y;
        #pragma unroll
        for (int m = 1; m < 32; m <<= 1) {
            s1 += __shfl_xor(s1, m, 64);
            s2 += __shfl_xor(s2, m, 64);
        }
        const float mean = s1 * (1.0f / VDIM);
        const float var  = s2 * (1.0f / VDIM) - mean * mean;
        const float rs   = __builtin_amdgcn_rsqf(var + 1e-5f);
        const float sel  = slg[v] * ((y - mean) * rs) + slb[v];
        float mx = sel;
        #pragma unroll
        for (int m = 1; m < 32; m <<= 1)
            mx = fmaxf(mx, __shfl_xor(mx, m, 64));
        const float e = __expf(sel - mx);
        float se = e;
        #pragma unroll
        for (int m = 1; m < 32; m <<= 1)
            se += __shfl_xor(se, m, 64);
        w_s[r][v] = e * __builtin_amdgcn_rcpf(se);
    }
    __syncthreads();

    // ---- Phase B: wave owns rows rA=2w, rB=2w+1; lane owns o-quad ----
    const int wave = tid >> 6;        // 0..3
    const int lane = tid & 63;
    const int o0   = lane << 2;
    const int rA   = wave * 2, rB = rA + 1;

    float aA0 = 0.f, aA1 = 0.f, aA2 = 0.f, aA3 = 0.f;
    float aB0 = 0.f, aB1 = 0.f, aB2 = 0.f, aB3 = 0.f;

    for (int c = 0; c < NCHUNK; ++c) {
        float4 pf[4];
        if (c < NCHUNK - 1) {
            #pragma unroll
            for (int k = 0; k < 4; ++k)
                pf[k] = *(const float4*)(sb[k] + (c + 1) * ss[k]);
        }

        const float* buf = wbuf[c & 1];

        #pragma unroll
        for (int v4 = 0; v4 < 2; ++v4) {
            const int v = c * 2 + v4;
            const float4 ga  = *(const float4*)(buf + v4 * 512 + o0);
            const float4 va  = *(const float4*)(buf + v4 * 512 + 256 + o0);
            const float4 gab = *(const float4*)(buf + 1024 + v4 * 512 + o0);
            const float4 vab = *(const float4*)(buf + 1024 + v4 * 512 + 256 + o0);
            const float4 sw4 = *(const float4*)(buf + 2048 + v4 * 256 + o0);
            const float4 sb4 = *(const float4*)(buf + 2560 + v4 * 256 + o0);
            const float4 lg4 = *(const float4*)(buf + 3072 + v4 * 256 + o0);
            const float4 lb4 = *(const float4*)(buf + 3584 + v4 * 256 + o0);

            const float xa = x_s[rA][v];     // LDS broadcast
            const float xb = x_s[rB][v];

            const float yA0 = fast_sigmoid(fmaf(xa, ga.x, gab.x)) * fmaf(xa, va.x, vab.x) + fmaf(xa, sw4.x, sb4.x);
            const float yA1 = fast_sigmoid(fmaf(xa, ga.y, gab.y)) * fmaf(xa, va.y, vab.y) + fmaf(xa, sw4.y, sb4.y);
            const float yA2 = fast_sigmoid(fmaf(xa, ga.z, gab.z)) * fmaf(xa, va.z, vab.z) + fmaf(xa, sw4.z, sb4.z);
            const float yA3 = fast_sigmoid(fmaf(xa, ga.w, gab.w)) * fmaf(xa, va.w, vab.w) + fmaf(xa, sw4.w, sb4.w);
            const float yB0 = fast_sigmoid(fmaf(xb, ga.x, gab.x)) * fmaf(xb, va.x, vab.x) + fmaf(xb, sw4.x, sb4.x);
            const float yB1 = fast_sigmoid(fmaf(xb, ga.y, gab.y)) * fmaf(xb, va.y, vab.y) + fmaf(xb, sw4.y, sb4.y);
            const float yB2 = fast_sigmoid(fmaf(xb, ga.z, gab.z)) * fmaf(xb, va.z, vab.z) + fmaf(xb, sw4.z, sb4.z);
            const float yB3 = fast_sigmoid(fmaf(xb, ga.w, gab.w)) * fmaf(xb, va.w, vab.w) + fmaf(xb, sw4.w, sb4.w);

            const float s1a = wave_sum((yA0 + yA1) + (yA2 + yA3));
            const float s2a = wave_sum(fmaf(yA0, yA0, fmaf(yA1, yA1, fmaf(yA2, yA2, yA3 * yA3))));
            const float s1b = wave_sum((yB0 + yB1) + (yB2 + yB3));
            const float s2b = wave_sum(fmaf(yB0, yB0, fmaf(yB1, yB1, fmaf(yB2, yB2, yB3 * yB3))));

            const float mA = s1a * (1.0f / ODIM);
            const float vA = s2a * (1.0f / ODIM) - mA * mA;
            const float rsA = __builtin_amdgcn_rsqf(vA + 1e-5f);
            const float wA = w_s[rA][v];
            const float wrsA = wA * rsA;
            aA0 = fmaf(lg4.x, (yA0 - mA) * wrsA, fmaf(wA, lb4.x, aA0));
            aA1 = fmaf(lg4.y, (yA1 - mA) * wrsA, fmaf(wA, lb4.y, aA1));
            aA2 = fmaf(lg4.z, (yA2 - mA) * wrsA, fmaf(wA, lb4.z, aA2));
            aA3 = fmaf(lg4.w, (yA3 - mA) * wrsA, fmaf(wA, lb4.w, aA3));

            const float mB = s1b * (1.0f / ODIM);
            const float vB = s2b * (1.0f / ODIM) - mB * mB;
            const float rsB = __builtin_amdgcn_rsqf(vB + 1e-5f);
            const float wB = w_s[rB][v];
            const float wrsB = wB * rsB;
            aB0 = fmaf(lg4.x, (yB0 - mB) * wrsB, fmaf(wB, lb4.x, aB0));
            aB1 = fmaf(lg4.y, (yB1 - mB) * wrsB, fmaf(wB, lb4.y, aB1));
            aB2 = fmaf(lg4.z, (yB2 - mB) * wrsB, fmaf(wB, lb4.z, aB2));
            aB3 = fmaf(lg4.w, (yB3 - mB) * wrsB, fmaf(wB, lb4.w, aB3));
        }

        if (c < NCHUNK - 1) {
            #pragma unroll
            for (int k = 0; k < 4; ++k)
                ((float4*)wbuf[(c + 1) & 1])[tid + k * TPB] = pf[k];
        }
        __syncthreads();
    }

    *(float4*)(out + (size_t)(row0 + rA) * ODIM + o0) = make_float4(aA0, aA1, aA2, aA3);
    *(float4*)(out + (size_t)(row0 + rB) * ODIM + o0) = make_float4(aB0, aB1, aB2, aB3);
}

extern "C" void kernel_launch(void* const* d_in, const int* in_sizes, int n_in,
                              void* d_out, int out_size, void* d_ws, size_t ws_size,
                              hipStream_t stream) {
    const float* x   = (const float*)d_in[0];
    const float* sgw = (const float*)d_in[5];
    const float* sgb = (const float*)d_in[6];
    const float* slg = (const float*)d_in[7];
    const float* slb = (const float*)d_in[8];
    const float* vgw = (const float*)d_in[13];
    const float* vgb = (const float*)d_in[14];
    const float* vsw = (const float*)d_in[15];
    const float* vsb = (const float*)d_in[16];
    const float* vlg = (const float*)d_in[17];
    const float* vlb = (const float*)d_in[18];
    float* out = (float*)d_out;

    const int N = in_sizes[0] / VDIM;      // 4096 rows
    const int grid = N / RPB;              // 512 blocks, 2 per CU

    vsn_fused<<<grid, TPB, 0, stream>>>(x, sgw, sgb, slg, slb,
                                        vgw, vgb, vsw, vsb, vlg, vlb, out);
}

// Round 6
// 117.047 us; speedup vs baseline: 1.1473x; 1.1473x over previous
//
#include <hip/hip_runtime.h>
#include <hip/hip_bf16.h>

// VariableSelectionNetwork fused kernel, round 6.
//
// Live computation (sel fc1/fc2 and the nvh,vho einsum are dead in the ref):
//   weights = softmax(LN(GLU(x @ sel_gate_w + b) + x))            [N,32]
//   y[n,v,o] = sigmoid(x*gw+gb)*(x*gw'+gb') + (x*sw+sb)           [N,32,256]
//   out[n,o] = sum_v weights[n,v] * LN_o(y)[.,v,.]                [N,256]
//
// R4 (LDS-staged weights, 16 waves/CU, shuffle reductions) ~= 40us kernel:
// LDS-instruction-bound (8 ds_read_b128 = 96clk + 12 ds_swizzle = 70clk per
// wave per v). R5 (RPW=2 + DPP + 8 waves/CU) regressed on scratch spills.
// R6 = exact R4 structure + DPP wave_sum only (verified correct in R5):
// removes the 70clk/v swizzle load from the LDS pipe, moves sums to VALU.

#define VDIM 32
#define ODIM 256
#define RPB  16          // rows per block == waves per block
#define TPB  1024
#define NCHUNK  16       // VDIM / 2 variables per chunk

__device__ __forceinline__ float fast_sigmoid(float g) {
    // 1 / (1 + exp(-g)); exp overflow -> inf -> rcp -> 0, correct limit.
    return __builtin_amdgcn_rcpf(1.0f + __expf(-g));
}

// DPP-add: x += dpp_moved(x), 0-filled for invalid source lanes. Pure VALU.
template <int CTRL>
__device__ __forceinline__ float dpp_add(float x) {
    int s = __builtin_amdgcn_update_dpp(0, __builtin_bit_cast(int, x),
                                        CTRL, 0xF, 0xF, true);
    return x + __builtin_bit_cast(float, s);
}

// Wave64 sum -> uniform value via readlane 63. No DS-pipe ops.
__device__ __forceinline__ float wave_sum(float x) {
    x = dpp_add<0x111>(x);   // row_shr:1
    x = dpp_add<0x112>(x);   // row_shr:2
    x = dpp_add<0x114>(x);   // row_shr:4
    x = dpp_add<0x118>(x);   // row_shr:8   -> lane 15 of each row-of-16 has row sum
    x = dpp_add<0x142>(x);   // row_bcast:15 -> lane 31 has half sum
    x = dpp_add<0x143>(x);   // row_bcast:31 -> lane 63 has total
    return __builtin_bit_cast(float,
        __builtin_amdgcn_readlane(__builtin_bit_cast(int, x), 63));
}

__global__ void __launch_bounds__(TPB) vsn_fused(
    const float* __restrict__ x,     // [N,32]
    const float* __restrict__ sgw,   // [32,64] sel_gate_w
    const float* __restrict__ sgb,   // [64]
    const float* __restrict__ slg,   // [32]
    const float* __restrict__ slb,   // [32]
    const float* __restrict__ vgw,   // [32,512]
    const float* __restrict__ vgb,   // [32,512]
    const float* __restrict__ vsw,   // [32,256]
    const float* __restrict__ vsb,   // [32,256]
    const float* __restrict__ vlg,   // [32,256]
    const float* __restrict__ vlb,   // [32,256]
    float* __restrict__ out)         // [N,256]
{
    // Chunk layout (floats), per buffer of 4096 floats (16KB), vars v=2c,2c+1:
    //   [0,1024) vgw | [1024,2048) vgb | [2048,2560) vsw | [2560,3072) vsb
    //   [3072,3584) vlg | [3584,4096) vlb
    __shared__ float wbuf[2][4096];          // 32KB double buffer
    __shared__ float x_s[RPB][VDIM];         // 2KB
    __shared__ float g_s[RPB][2 * VDIM];     // 4KB
    __shared__ float w_s[RPB][VDIM];         // 2KB

    const int tid  = threadIdx.x;
    const int row0 = blockIdx.x * RPB;

    // ---- per-thread staging source (loop-invariant base + per-chunk stride) ----
    const float* sbase;
    int sstr;
    if (tid < 256)      { sbase = vgw + (tid << 2);         sstr = 1024; }
    else if (tid < 512) { sbase = vgb + ((tid - 256) << 2); sstr = 1024; }
    else if (tid < 640) { sbase = vsw + ((tid - 512) << 2); sstr = 512;  }
    else if (tid < 768) { sbase = vsb + ((tid - 640) << 2); sstr = 512;  }
    else if (tid < 896) { sbase = vlg + ((tid - 768) << 2); sstr = 512;  }
    else                { sbase = vlb + ((tid - 896) << 2); sstr = 512;  }

    // ---- issue chunk-0 staging load early (hides under Phase A) ----
    const float4 st0 = *(const float4*)sbase;

    // ---- load x rows (16*32 = 512 floats) ----
    if (tid < RPB * VDIM)
        ((float*)x_s)[tid] = x[row0 * VDIM + tid];
    __syncthreads();

    // ---- Phase A1: g = x @ sel_gate_w + sel_gate_b (16 rows x 64 cols) ----
    {
        const int r = tid >> 6, j = tid & 63;   // 1024 tasks == TPB
        float acc = sgb[j];
        #pragma unroll
        for (int v = 0; v < VDIM; ++v)
            acc = fmaf(x_s[r][v], sgw[v * 64 + j], acc);
        g_s[r][j] = acc;
    }
    __syncthreads();

    // ---- write chunk 0 into buffer 0 (all threads); Phase A2 on 512 threads ----
    ((float4*)wbuf[0])[tid] = st0;

    if (tid < RPB * VDIM) {
        const int r = tid >> 5, v = tid & 31;
        const float gate = g_s[r][v];
        const float val  = g_s[r][VDIM + v];
        const float y    = fast_sigmoid(gate) * val + x_s[r][v];
        float s1 = y, s2 = y * y;
        #pragma unroll
        for (int m = 1; m < 32; m <<= 1) {
            s1 += __shfl_xor(s1, m, 64);
            s2 += __shfl_xor(s2, m, 64);
        }
        const float mean = s1 * (1.0f / VDIM);
        const float var  = s2 * (1.0f / VDIM) - mean * mean;
        const float rs   = __builtin_amdgcn_rsqf(var + 1e-5f);
        const float sel  = slg[v] * ((y - mean) * rs) + slb[v];
        float mx = sel;
        #pragma unroll
        for (int m = 1; m < 32; m <<= 1)
            mx = fmaxf(mx, __shfl_xor(mx, m, 64));
        const float e = __expf(sel - mx);
        float se = e;
        #pragma unroll
        for (int m = 1; m < 32; m <<= 1)
            se += __shfl_xor(se, m, 64);
        w_s[r][v] = e * __builtin_amdgcn_rcpf(se);
    }
    __syncthreads();

    // ---- Phase B: wave = row; lane owns o-quad [4l, 4l+3] ----
    const int wave = tid >> 6;        // 0..15 == row within block
    const int lane = tid & 63;
    const int o0   = lane << 2;

    float acc0 = 0.0f, acc1 = 0.0f, acc2 = 0.0f, acc3 = 0.0f;

    for (int c = 0; c < NCHUNK; ++c) {
        // issue next chunk's staging load (1 float4/thread) before compute
        float4 pf;
        if (c < NCHUNK - 1)
            pf = *(const float4*)(sbase + (c + 1) * sstr);

        const float* buf = wbuf[c & 1];

        #pragma unroll
        for (int v4 = 0; v4 < 2; ++v4) {
            const int v = c * 2 + v4;
            const float4 ga  = *(const float4*)(buf + v4 * 512 + o0);
            const float4 va  = *(const float4*)(buf + v4 * 512 + 256 + o0);
            const float4 gab = *(const float4*)(buf + 1024 + v4 * 512 + o0);
            const float4 vab = *(const float4*)(buf + 1024 + v4 * 512 + 256 + o0);
            const float4 sw4 = *(const float4*)(buf + 2048 + v4 * 256 + o0);
            const float4 sb4 = *(const float4*)(buf + 2560 + v4 * 256 + o0);
            const float4 lg4 = *(const float4*)(buf + 3072 + v4 * 256 + o0);
            const float4 lb4 = *(const float4*)(buf + 3584 + v4 * 256 + o0);

            const float xv = x_s[wave][v];   // LDS broadcast

            const float y0 = fast_sigmoid(fmaf(xv, ga.x, gab.x)) * fmaf(xv, va.x, vab.x) + fmaf(xv, sw4.x, sb4.x);
            const float y1 = fast_sigmoid(fmaf(xv, ga.y, gab.y)) * fmaf(xv, va.y, vab.y) + fmaf(xv, sw4.y, sb4.y);
            const float y2 = fast_sigmoid(fmaf(xv, ga.z, gab.z)) * fmaf(xv, va.z, vab.z) + fmaf(xv, sw4.z, sb4.z);
            const float y3 = fast_sigmoid(fmaf(xv, ga.w, gab.w)) * fmaf(xv, va.w, vab.w) + fmaf(xv, sw4.w, sb4.w);

            // LN sums on the VALU pipe (DPP), not the DS pipe.
            const float s1 = wave_sum((y0 + y1) + (y2 + y3));
            const float s2 = wave_sum(fmaf(y0, y0, fmaf(y1, y1, fmaf(y2, y2, y3 * y3))));

            const float mean = s1 * (1.0f / ODIM);
            const float var  = s2 * (1.0f / ODIM) - mean * mean;
            const float rs   = __builtin_amdgcn_rsqf(var + 1e-5f);
            const float wv   = w_s[wave][v];
            const float wrs  = wv * rs;
            acc0 = fmaf(lg4.x, (y0 - mean) * wrs, fmaf(wv, lb4.x, acc0));
            acc1 = fmaf(lg4.y, (y1 - mean) * wrs, fmaf(wv, lb4.y, acc1));
            acc2 = fmaf(lg4.z, (y2 - mean) * wrs, fmaf(wv, lb4.z, acc2));
            acc3 = fmaf(lg4.w, (y3 - mean) * wrs, fmaf(wv, lb4.w, acc3));
        }

        // write next chunk; one barrier per chunk covers both the new writes
        // and the end-of-read of buf[c&1] (overwritten at c+2).
        if (c < NCHUNK - 1)
            ((float4*)wbuf[(c + 1) & 1])[tid] = pf;
        __syncthreads();
    }

    float4 o4 = make_float4(acc0, acc1, acc2, acc3);
    *(float4*)(out + (size_t)(row0 + wave) * ODIM + o0) = o4;
}

extern "C" void kernel_launch(void* const* d_in, const int* in_sizes, int n_in,
                              void* d_out, int out_size, void* d_ws, size_t ws_size,
                              hipStream_t stream) {
    const float* x   = (const float*)d_in[0];
    const float* sgw = (const float*)d_in[5];
    const float* sgb = (const float*)d_in[6];
    const float* slg = (const float*)d_in[7];
    const float* slb = (const float*)d_in[8];
    const float* vgw = (const float*)d_in[13];
    const float* vgb = (const float*)d_in[14];
    const float* vsw = (const float*)d_in[15];
    const float* vsb = (const float*)d_in[16];
    const float* vlg = (const float*)d_in[17];
    const float* vlb = (const float*)d_in[18];
    float* out = (float*)d_out;

    const int N = in_sizes[0] / VDIM;      // 4096 rows
    const int grid = N / RPB;              // 256 blocks, 1 per CU

    vsn_fused<<<grid, TPB, 0, stream>>>(x, sgw, sgb, slg, slb,
                                        vgw, vgb, vsw, vsb, vlg, vlb, out);
}

// Round 7
// 115.552 us; speedup vs baseline: 1.1621x; 1.0129x over previous
//
#include <hip/hip_runtime.h>
#include <hip/hip_bf16.h>

// VariableSelectionNetwork fused kernel, round 7.
//
// Live computation (sel fc1/fc2 and the nvh,vho einsum are dead in the ref):
//   weights = softmax(LN(GLU(x @ sel_gate_w + b) + x))            [N,32]
//   y[n,v,o] = sigmoid(x*gw+gb)*(x*gw'+gb') + (x*sw+sb)           [N,32,256]
//   out[n,o] = sum_v weights[n,v] * LN_o(y)[.,v,.]                [N,256]
//
// R6 (LDS-staged + DPP sums) ~= 32us: LDS pipe bound by 16x redundant weight
// reads (16 waves x 8 ds_read_b128 per v). R7 halves redundancy: RPW=2 (one
// weight read serves rows 2w, 2w+1). R5 tried this and spilled — diagnosis:
// sb[]/ss[]/pf[] arrays went to scratch (rule: runtime-indexed arrays ->
// localMem), NOT a VGPR shortage. Fix: named scalar pointers + pointer-bump,
// no arrays, __launch_bounds__(256) only. 2 blocks/CU for barrier decoupling.

#define VDIM 32
#define ODIM 256
#define RPB  8           // rows per block
#define TPB  256         // 4 waves; wave w owns rows 2w, 2w+1
#define NCHUNK 16        // VDIM/2 variables per chunk

__device__ __forceinline__ float fast_sigmoid(float g) {
    // 1 / (1 + exp(-g)); exp overflow -> inf -> rcp -> 0, correct limit.
    return __builtin_amdgcn_rcpf(1.0f + __expf(-g));
}

// DPP-add: x += dpp_moved(x), 0-filled for invalid source lanes. Pure VALU.
template <int CTRL>
__device__ __forceinline__ float dpp_add(float x) {
    int s = __builtin_amdgcn_update_dpp(0, __builtin_bit_cast(int, x),
                                        CTRL, 0xF, 0xF, true);
    return x + __builtin_bit_cast(float, s);
}

// Wave64 sum -> uniform value via readlane 63. No DS-pipe ops.
__device__ __forceinline__ float wave_sum(float x) {
    x = dpp_add<0x111>(x);   // row_shr:1
    x = dpp_add<0x112>(x);   // row_shr:2
    x = dpp_add<0x114>(x);   // row_shr:4
    x = dpp_add<0x118>(x);   // row_shr:8
    x = dpp_add<0x142>(x);   // row_bcast:15
    x = dpp_add<0x143>(x);   // row_bcast:31 -> lane 63 holds total
    return __builtin_bit_cast(float,
        __builtin_amdgcn_readlane(__builtin_bit_cast(int, x), 63));
}

__global__ void __launch_bounds__(TPB) vsn_fused(
    const float* __restrict__ x,     // [N,32]
    const float* __restrict__ sgw,   // [32,64]
    const float* __restrict__ sgb,   // [64]
    const float* __restrict__ slg,   // [32]
    const float* __restrict__ slb,   // [32]
    const float* __restrict__ vgw,   // [32,512]
    const float* __restrict__ vgb,   // [32,512]
    const float* __restrict__ vsw,   // [32,256]
    const float* __restrict__ vsb,   // [32,256]
    const float* __restrict__ vlg,   // [32,256]
    const float* __restrict__ vlb,   // [32,256]
    float* __restrict__ out)         // [N,256]
{
    // Chunk image (4096 floats = 16KB), vars v=2c,2c+1:
    //   [0,1024) vgw | [1024,2048) vgb | [2048,2560) vsw | [2560,3072) vsb
    //   [3072,3584) vlg | [3584,4096) vlb
    // float4 slots: vgw [0,256) | vgb [256,512) | vsw [512,640) | vsb [640,768)
    //   vlg [768,896) | vlb [896,1024)
    __shared__ float wbuf[2][4096];          // 32KB double buffer
    __shared__ float x_s[RPB][VDIM];         // 1KB
    __shared__ float g_s[RPB][2 * VDIM];     // 2KB
    __shared__ float w_s[RPB][VDIM];         // 1KB

    const int tid  = threadIdx.x;
    const int row0 = blockIdx.x * RPB;

    // ---- staging sources: thread t owns float4 slots t, t+256, t+512, t+768.
    // Named scalar pointers (NO arrays -> no scratch). tid<128 is wave-uniform.
    const float* p0 = vgw + (tid << 2);
    const float* p1 = vgb + (tid << 2);
    const float* p2 = (tid < 128 ? vsw : vsb - 512) + (tid << 2);
    const float* p3 = (tid < 128 ? vlg : vlb - 512) + (tid << 2);

    // ---- issue chunk-0 staging loads early (hide under Phase A) ----
    const float4 st0 = *(const float4*)p0;  p0 += 1024;
    const float4 st1 = *(const float4*)p1;  p1 += 1024;
    const float4 st2 = *(const float4*)p2;  p2 += 512;
    const float4 st3 = *(const float4*)p3;  p3 += 512;

    // ---- load x rows (8*32 = 256 floats == TPB) ----
    ((float*)x_s)[tid] = x[row0 * VDIM + tid];
    __syncthreads();

    // ---- Phase A1: g = x @ sel_gate_w + b (8 rows x 64 cols, 2 tasks/thread) ----
    #pragma unroll
    for (int it = 0; it < 2; ++it) {
        const int i = tid + it * TPB;
        const int r = i >> 6, j = i & 63;
        float acc = sgb[j];
        #pragma unroll
        for (int v = 0; v < VDIM; ++v)
            acc = fmaf(x_s[r][v], sgw[v * 64 + j], acc);
        g_s[r][j] = acc;
    }
    __syncthreads();

    // ---- write chunk 0 into buffer 0; Phase A2 on all 256 threads ----
    {
        float4* wb = (float4*)wbuf[0];
        wb[tid]       = st0;
        wb[tid + 256] = st1;
        wb[tid + 512] = st2;
        wb[tid + 768] = st3;
    }

    {
        const int r = tid >> 5, v = tid & 31;    // 256 tasks == TPB
        const float gate = g_s[r][v];
        const float val  = g_s[r][VDIM + v];
        const float y    = fast_sigmoid(gate) * val + x_s[r][v];
        float s1 = y, s2 = y * y;
        #pragma unroll
        for (int m = 1; m < 32; m <<= 1) {
            s1 += __shfl_xor(s1, m, 64);
            s2 += __shfl_xor(s2, m, 64);
        }
        const float mean = s1 * (1.0f / VDIM);
        const float var  = s2 * (1.0f / VDIM) - mean * mean;
        const float rs   = __builtin_amdgcn_rsqf(var + 1e-5f);
        const float sel  = slg[v] * ((y - mean) * rs) + slb[v];
        float mx = sel;
        #pragma unroll
        for (int m = 1; m < 32; m <<= 1)
            mx = fmaxf(mx, __shfl_xor(mx, m, 64));
        const float e = __expf(sel - mx);
        float se = e;
        #pragma unroll
        for (int m = 1; m < 32; m <<= 1)
            se += __shfl_xor(se, m, 64);
        w_s[r][v] = e * __builtin_amdgcn_rcpf(se);
    }
    __syncthreads();

    // ---- Phase B: wave owns rows rA=2w, rB=2w+1; lane owns o-quad ----
    const int wave = tid >> 6;        // 0..3
    const int lane = tid & 63;
    const int o0   = lane << 2;
    const int rA   = wave * 2, rB = rA + 1;

    float aA0 = 0.f, aA1 = 0.f, aA2 = 0.f, aA3 = 0.f;
    float aB0 = 0.f, aB1 = 0.f, aB2 = 0.f, aB3 = 0.f;

    for (int c = 0; c < NCHUNK; ++c) {
        // prefetch next chunk into named scalars (issue before compute)
        float4 q0, q1, q2, q3;
        if (c < NCHUNK - 1) {
            q0 = *(const float4*)p0;  p0 += 1024;
            q1 = *(const float4*)p1;  p1 += 1024;
            q2 = *(const float4*)p2;  p2 += 512;
            q3 = *(const float4*)p3;  p3 += 512;
        }

        const float* buf = wbuf[c & 1];

        #pragma unroll
        for (int v4 = 0; v4 < 2; ++v4) {
            const int v = c * 2 + v4;
            const float4 ga  = *(const float4*)(buf + v4 * 512 + o0);
            const float4 va  = *(const float4*)(buf + v4 * 512 + 256 + o0);
            const float4 gab = *(const float4*)(buf + 1024 + v4 * 512 + o0);
            const float4 vab = *(const float4*)(buf + 1024 + v4 * 512 + 256 + o0);
            const float4 sw4 = *(const float4*)(buf + 2048 + v4 * 256 + o0);
            const float4 sb4 = *(const float4*)(buf + 2560 + v4 * 256 + o0);
            const float4 lg4 = *(const float4*)(buf + 3072 + v4 * 256 + o0);
            const float4 lb4 = *(const float4*)(buf + 3584 + v4 * 256 + o0);

            const float xa = x_s[rA][v];     // LDS broadcast
            const float xb = x_s[rB][v];

            const float yA0 = fast_sigmoid(fmaf(xa, ga.x, gab.x)) * fmaf(xa, va.x, vab.x) + fmaf(xa, sw4.x, sb4.x);
            const float yA1 = fast_sigmoid(fmaf(xa, ga.y, gab.y)) * fmaf(xa, va.y, vab.y) + fmaf(xa, sw4.y, sb4.y);
            const float yA2 = fast_sigmoid(fmaf(xa, ga.z, gab.z)) * fmaf(xa, va.z, vab.z) + fmaf(xa, sw4.z, sb4.z);
            const float yA3 = fast_sigmoid(fmaf(xa, ga.w, gab.w)) * fmaf(xa, va.w, vab.w) + fmaf(xa, sw4.w, sb4.w);
            const float yB0 = fast_sigmoid(fmaf(xb, ga.x, gab.x)) * fmaf(xb, va.x, vab.x) + fmaf(xb, sw4.x, sb4.x);
            const float yB1 = fast_sigmoid(fmaf(xb, ga.y, gab.y)) * fmaf(xb, va.y, vab.y) + fmaf(xb, sw4.y, sb4.y);
            const float yB2 = fast_sigmoid(fmaf(xb, ga.z, gab.z)) * fmaf(xb, va.z, vab.z) + fmaf(xb, sw4.z, sb4.z);
            const float yB3 = fast_sigmoid(fmaf(xb, ga.w, gab.w)) * fmaf(xb, va.w, vab.w) + fmaf(xb, sw4.w, sb4.w);

            // four independent DPP chains (ILP)
            const float s1a = wave_sum((yA0 + yA1) + (yA2 + yA3));
            const float s2a = wave_sum(fmaf(yA0, yA0, fmaf(yA1, yA1, fmaf(yA2, yA2, yA3 * yA3))));
            const float s1b = wave_sum((yB0 + yB1) + (yB2 + yB3));
            const float s2b = wave_sum(fmaf(yB0, yB0, fmaf(yB1, yB1, fmaf(yB2, yB2, yB3 * yB3))));

            const float mA  = s1a * (1.0f / ODIM);
            const float vA  = s2a * (1.0f / ODIM) - mA * mA;
            const float rsA = __builtin_amdgcn_rsqf(vA + 1e-5f);
            const float wA  = w_s[rA][v];
            const float wrsA = wA * rsA;
            aA0 = fmaf(lg4.x, (yA0 - mA) * wrsA, fmaf(wA, lb4.x, aA0));
            aA1 = fmaf(lg4.y, (yA1 - mA) * wrsA, fmaf(wA, lb4.y, aA1));
            aA2 = fmaf(lg4.z, (yA2 - mA) * wrsA, fmaf(wA, lb4.z, aA2));
            aA3 = fmaf(lg4.w, (yA3 - mA) * wrsA, fmaf(wA, lb4.w, aA3));

            const float mB  = s1b * (1.0f / ODIM);
            const float vB  = s2b * (1.0f / ODIM) - mB * mB;
            const float rsB = __builtin_amdgcn_rsqf(vB + 1e-5f);
            const float wB  = w_s[rB][v];
            const float wrsB = wB * rsB;
            aB0 = fmaf(lg4.x, (yB0 - mB) * wrsB, fmaf(wB, lb4.x, aB0));
            aB1 = fmaf(lg4.y, (yB1 - mB) * wrsB, fmaf(wB, lb4.y, aB1));
            aB2 = fmaf(lg4.z, (yB2 - mB) * wrsB, fmaf(wB, lb4.z, aB2));
            aB3 = fmaf(lg4.w, (yB3 - mB) * wrsB, fmaf(wB, lb4.w, aB3));
        }

        // write next chunk; one barrier per chunk covers the new writes and
        // the end-of-read of buf[c&1] (overwritten at c+2).
        if (c < NCHUNK - 1) {
            float4* wb = (float4*)wbuf[(c + 1) & 1];
            wb[tid]       = q0;
            wb[tid + 256] = q1;
            wb[tid + 512] = q2;
            wb[tid + 768] = q3;
        }
        __syncthreads();
    }

    *(float4*)(out + (size_t)(row0 + rA) * ODIM + o0) = make_float4(aA0, aA1, aA2, aA3);
    *(float4*)(out + (size_t)(row0 + rB) * ODIM + o0) = make_float4(aB0, aB1, aB2, aB3);
}

extern "C" void kernel_launch(void* const* d_in, const int* in_sizes, int n_in,
                              void* d_out, int out_size, void* d_ws, size_t ws_size,
                              hipStream_t stream) {
    const float* x   = (const float*)d_in[0];
    const float* sgw = (const float*)d_in[5];
    const float* sgb = (const float*)d_in[6];
    const float* slg = (const float*)d_in[7];
    const float* slb = (const float*)d_in[8];
    const float* vgw = (const float*)d_in[13];
    const float* vgb = (const float*)d_in[14];
    const float* vsw = (const float*)d_in[15];
    const float* vsb = (const float*)d_in[16];
    const float* vlg = (const float*)d_in[17];
    const float* vlb = (const float*)d_in[18];
    float* out = (float*)d_out;

    const int N = in_sizes[0] / VDIM;      // 4096 rows
    const int grid = N / RPB;              // 512 blocks, 2 per CU

    vsn_fused<<<grid, TPB, 0, stream>>>(x, sgw, sgb, slg, slb,
                                        vgw, vgb, vsw, vsb, vlg, vlb, out);
}